// Round 3
// baseline (149.374 us; speedup 1.0000x reference)
//
#include <hip/hip_runtime.h>
#include <stdint.h>

// ColBERT MaxSim on MI355X (gfx950), round 9.
// scores[b,c] = sum_n max_s dot(qs[b,n,:], ps[c,s,:])
// qs: (64, 32, 128) f32, ps: (64, 1024, 128) f32, out: (64, 64) f32.
//
// R8 post-mortem: VGPR_Count=128 AGAIN (R7: 120) with WRITE_SIZE 3.6 MB of
// scratch spill. Demand (~236) was under the 256 cap, so the allocator is
// CHOOSING 128 regs: __launch_bounds__(256,2) only sets MIN waves/EU, and
// the scheduler still chases 4 waves/EU (128-reg budget), demoting qf to
// LDS re-reads + scratch to get there. Per-MFMA fetch back to ~1 KB ->
// MfmaUtil 15%, maxsim 86 us.
//
// R9: one-variable fix -- __attribute__((amdgpu_waves_per_eu(2,2))) pins
// BOTH min and max occupancy at 2 waves/EU, fixing the allocator budget at
// 256 VGPRs and removing the incentive to shrink. Structure identical to R8:
//   - qf[4][8] B-frags register-resident (128 VGPRs), read from LDS ONCE
//   - single bf16 A-buffer a[8] (32), half-tile f32 staging F[8] (32)
//   - pass2 split at k=4 gives the WAR-free window for in-place a[] refresh
//   Peak live ~ 236 < 256.
// Pass signal: VGPR >= 224, WRITE_SIZE ~32 KB. Predict MfmaUtil 40-60%,
// maxsim 22-35 us. If VGPR pins at 128 again, fallback is 2 queries/wave.
//
// Carried: XCD swizzle keeps each doc's P in one XCD's L2; no d_ws use
// (the 256 MiB ws poison fill is conditional on ws use -- R7/R8 confirmed
// it vanished).

typedef __bf16 bf16x8 __attribute__((ext_vector_type(8)));
typedef float floatx16 __attribute__((ext_vector_type(16)));

union FragU { uint4 u; bf16x8 v; };

// Two uint4-loaded f32 quads -> one bf16x8 frag (v_cvt_pk_bf16_f32 pairs).
__device__ inline bf16x8 cvt2(const uint4& lo, const uint4& hi) {
  union { uint4 u; float f[4]; } a, b;
  a.u = lo; b.u = hi;
  bf16x8 r;
  r[0] = (__bf16)a.f[0]; r[1] = (__bf16)a.f[1]; r[2] = (__bf16)a.f[2]; r[3] = (__bf16)a.f[3];
  r[4] = (__bf16)b.f[0]; r[5] = (__bf16)b.f[1]; r[6] = (__bf16)b.f[2]; r[7] = (__bf16)b.f[3];
  return r;
}

__device__ inline float rmax16(const floatx16& a) {
  // Nested fmaxf triples fuse to v_max3_f32.
  float m0 = fmaxf(fmaxf(a[0], a[1]), fmaxf(a[2], a[3]));
  float m1 = fmaxf(fmaxf(a[4], a[5]), fmaxf(a[6], a[7]));
  float m2 = fmaxf(fmaxf(a[8], a[9]), fmaxf(a[10], a[11]));
  float m3 = fmaxf(fmaxf(a[12], a[13]), fmaxf(a[14], a[15]));
  return fmaxf(fmaxf(m0, m1), fmaxf(m2, m3));
}

#define ZERO16 {0, 0, 0, 0, 0, 0, 0, 0, 0, 0, 0, 0, 0, 0, 0, 0}

__global__ __attribute__((amdgpu_waves_per_eu(2, 2))) __launch_bounds__(256)
void maxsim_kernel(const float* __restrict__ qs,
                   const float* __restrict__ ps,
                   float* __restrict__ out) {
  const int lane = threadIdx.x & 63;
  const int wave = threadIdx.x >> 6;

  // XCD-aware swizzle: all 16 blocks of doc c land on one XCD -> P_c stays
  // in that XCD's 4 MiB L2 (512 KB f32 per doc, ~4-5 docs resident).
  const int xcd = blockIdx.x & 7;
  const int slot = blockIdx.x >> 3;
  const int c = xcd * 8 + (slot >> 4);
  const int bg = slot & 15;
  const int b0 = bg * 4;
  const int row = lane & 31;         // A: s-row in tile; B frag: query token n
  const int koff = (lane >> 5) * 8;  // K-half selector

  // Stage Q in MFMA B-fragment order: frag id = (b*8 + k)*64 + lane, 16 B each.
  __shared__ ushort lds_q[4 * 8 * 64 * 8];  // 32 KiB
  {
    uint4* dst = (uint4*)lds_q;
#pragma unroll
    for (int i = 0; i < 8; ++i) {
      const int id = threadIdx.x + i * 256;  // 0..2047
      const int l = id & 63;
      const int k = (id >> 6) & 7;
      const int b = id >> 9;
      const int goff = ((b0 + b) * 32 + (l & 31)) * 128 + k * 16 + (l >> 5) * 8;
      const float* q = qs + goff;
      uint4 lo = *(const uint4*)q;
      uint4 hi = *(const uint4*)(q + 4);
      FragU f;
      f.v = cvt2(lo, hi);
      dst[id] = f.u;  // consecutive threads -> consecutive 16 B: conflict-free
    }
  }
  __syncthreads();

  // Pull ALL Q fragments into registers ONCE (32 x ds_read_b128, 128 VGPRs).
  // B-operand layout: B[n = lane&31][k = (lane>>5)*8 + j].
  const ushort* lq = lds_q + lane * 8;
  bf16x8 qf[4][8];
#pragma unroll
  for (int b = 0; b < 4; ++b)
#pragma unroll
    for (int k = 0; k < 8; ++k)
      qf[b][k] = *(const bf16x8*)(lq + (b * 8 + k) * 512);

  // Wave covers s in [wave*256, wave*256+256): 8 tiles of 32 doc tokens.
  const int pbase = (c * 1024 + wave * 256 + row) * 128 + koff;

  // Prologue: tile 0 loaded and converted.
  bf16x8 a[8];
#pragma unroll
  for (int j = 0; j < 8; ++j) {
    const float* p = ps + pbase + j * 16;
    uint4 lo = *(const uint4*)p;
    uint4 hi = *(const uint4*)(p + 4);
    a[j] = cvt2(lo, hi);
  }

  float vmax[4];
#pragma unroll
  for (int b = 0; b < 4; ++b) vmax[b] = -3.4e38f;

#pragma unroll 1
  for (int t = 0; t < 8; ++t) {
    const int tn = (t + 1) & 7;  // wrap: harmless L2-hot re-read on last iter
    const float* pn = ps + pbase + tn * 4096;

    // Stage half 1: issue f32 loads for next-tile frags 0..3 (32 VGPRs).
    uint4 F[8];
#pragma unroll
    for (int j = 0; j < 4; ++j) {
      F[2 * j] = *(const uint4*)(pn + j * 16);
      F[2 * j + 1] = *(const uint4*)(pn + j * 16 + 4);
    }

    // Pass 1: query blocks 0,1 over full K (16 MFMA).
    {
      floatx16 acc0 = ZERO16, acc1 = ZERO16;
#pragma unroll
      for (int k = 0; k < 8; ++k) {
        acc0 = __builtin_amdgcn_mfma_f32_32x32x16_bf16(a[k], qf[0][k], acc0, 0, 0, 0);
        acc1 = __builtin_amdgcn_mfma_f32_32x32x16_bf16(a[k], qf[1][k], acc1, 0, 0, 0);
      }
      vmax[0] = fmaxf(vmax[0], rmax16(acc0));
      vmax[1] = fmaxf(vmax[1], rmax16(acc1));
    }

    // Pass 2: query blocks 2,3; split at k=4 so a[0..3] can be overwritten.
    floatx16 acc2 = ZERO16, acc3 = ZERO16;
#pragma unroll
    for (int k = 0; k < 4; ++k) {
      acc2 = __builtin_amdgcn_mfma_f32_32x32x16_bf16(a[k], qf[2][k], acc2, 0, 0, 0);
      acc3 = __builtin_amdgcn_mfma_f32_32x32x16_bf16(a[k], qf[3][k], acc3, 0, 0, 0);
    }
    // a[0..3] dead for this tile: convert staged half 1 in place.
    a[0] = cvt2(F[0], F[1]);
    a[1] = cvt2(F[2], F[3]);
    a[2] = cvt2(F[4], F[5]);
    a[3] = cvt2(F[6], F[7]);
    // Stage half 2 into the same F registers.
#pragma unroll
    for (int j = 0; j < 4; ++j) {
      F[2 * j] = *(const uint4*)(pn + (4 + j) * 16);
      F[2 * j + 1] = *(const uint4*)(pn + (4 + j) * 16 + 4);
    }
#pragma unroll
    for (int k = 4; k < 8; ++k) {
      acc2 = __builtin_amdgcn_mfma_f32_32x32x16_bf16(a[k], qf[2][k], acc2, 0, 0, 0);
      acc3 = __builtin_amdgcn_mfma_f32_32x32x16_bf16(a[k], qf[3][k], acc3, 0, 0, 0);
    }
    vmax[2] = fmaxf(vmax[2], rmax16(acc2));
    vmax[3] = fmaxf(vmax[3], rmax16(acc3));
    // Convert staged half 2 (needed first at next tile's pass-1 k=4).
    a[4] = cvt2(F[0], F[1]);
    a[5] = cvt2(F[2], F[3]);
    a[6] = cvt2(F[4], F[5]);
    a[7] = cvt2(F[6], F[7]);
  }

  // Lanes l and l^32 hold complementary row-halves of the same query-token col.
#pragma unroll
  for (int b = 0; b < 4; ++b) vmax[b] = fmaxf(vmax[b], __shfl_xor(vmax[b], 32, 64));

  // Cross-wave max, then sum over the 32 query tokens.
  __shared__ float red[4][4][32];  // [wave][b][n]
  if (lane < 32) {
#pragma unroll
    for (int b = 0; b < 4; ++b) red[wave][b][lane] = vmax[b];
  }
  __syncthreads();
  if (threadIdx.x < 128) {
    const int b = threadIdx.x >> 5;
    const int n = threadIdx.x & 31;
    float m = fmaxf(fmaxf(red[0][b][n], red[1][b][n]), fmaxf(red[2][b][n], red[3][b][n]));
#pragma unroll
    for (int o = 16; o > 0; o >>= 1) m += __shfl_xor(m, o, 32);
    if (n == 0) out[(b0 + b) * 64 + c] = m;
  }
}

extern "C" void kernel_launch(void* const* d_in, const int* in_sizes, int n_in,
                              void* d_out, int out_size, void* d_ws, size_t ws_size,
                              hipStream_t stream) {
  const float* qs = (const float*)d_in[0];
  const float* ps = (const float*)d_in[1];
  float* out = (float*)d_out;
  (void)d_ws; (void)ws_size;  // deliberately unused: avoid the 256 MiB ws poison

  maxsim_kernel<<<dim3(64 * 16), dim3(256), 0, stream>>>(qs, ps, out);
}

// Round 4
// 116.741 us; speedup vs baseline: 1.2795x; 1.2795x over previous
//
#include <hip/hip_runtime.h>
#include <stdint.h>

// ColBERT MaxSim on MI355X (gfx950), round 10.
// scores[b,c] = sum_n max_s dot(qs[b,n,:], ps[c,s,:])
// qs: (64, 32, 128) f32, ps: (64, 1024, 128) f32, out: (64, 64) f32.
//
// R7-R9 post-mortem: the fused f32 path is a dead end -- LLVM rematerializes
// LDS-loaded Q fragments under pressure (VGPR pinned at 120-128 across
// launch_bounds(256,2) AND amdgpu_waves_per_eu(2,2)), so per-MFMA operand
// fetch stays ~1 KB f32 and MfmaUtil stays 15% (86-88 us). Meanwhile R7-R9
// DID prove the 256 MiB d_ws poison fill (46 us/iter) is conditional on
// touching d_ws.
//
// R10: recombine the two proven facts. Keep R6's PRECVT maxsim verbatim
// (bf16 operands in memory, A-frags global->reg at 16 B/lane, ~45-55 us,
// MfmaUtil ~22%) but stage the bf16 copy in a module-scope __device__
// array (16.5 MiB .bss, allocated at module load -- legal, no hipMalloc,
// graph-safe) instead of d_ws. cvt f32->bf16 happens ONCE per element
// (vs 16x redundant in the fused design). No workspace => no poison fill.
// Predict: cvt ~8 us, maxsim ~45-60 us (MfmaUtil ~22%, FETCH ~10 MB,
// WRITE ~32 KB), total 148 -> ~70-85 us.

typedef __bf16 bf16x8 __attribute__((ext_vector_type(8)));
typedef float floatx16 __attribute__((ext_vector_type(16)));

#define QS_N (64u * 32u * 128u)    // 262144
#define PS_N (64u * 1024u * 128u)  // 8388608

// Static bf16 staging buffer: qs in [0, QS_N), ps in [QS_N, QS_N+PS_N).
__device__ ushort g_bf[QS_N + PS_N];

// Fused cvt: first QS_N/4 float4s from qs, rest from ps.
__global__ __launch_bounds__(256) void cvt_kernel(const float* __restrict__ qs,
                                                  const float* __restrict__ ps) {
  const int nq4 = QS_N / 4;
  const int n4 = (QS_N + PS_N) / 4;
  int i = blockIdx.x * 256 + threadIdx.x;
  if (i >= n4) return;
  float4 f;
  if (i < nq4) {
    f = ((const float4*)qs)[i];
  } else {
    f = ((const float4*)ps)[i - nq4];
  }
  union { ushort4 s; struct { __bf16 a, b, c, d; } h; } o;
  o.h.a = (__bf16)f.x; o.h.b = (__bf16)f.y; o.h.c = (__bf16)f.z; o.h.d = (__bf16)f.w;
  ((ushort4*)g_bf)[i] = o.s;
}

union FragU { uint4 u; bf16x8 v; };

__device__ inline bf16x8 load_frag_bf16(const ushort* p) {
  FragU f;
  f.u = *(const uint4*)p;
  return f.v;
}

__device__ inline float rmax16(const floatx16& a) {
  // Nested fmaxf triples fuse to v_max3_f32.
  float m0 = fmaxf(fmaxf(a[0], a[1]), fmaxf(a[2], a[3]));
  float m1 = fmaxf(fmaxf(a[4], a[5]), fmaxf(a[6], a[7]));
  float m2 = fmaxf(fmaxf(a[8], a[9]), fmaxf(a[10], a[11]));
  float m3 = fmaxf(fmaxf(a[12], a[13]), fmaxf(a[14], a[15]));
  return fmaxf(fmaxf(m0, m1), fmaxf(m2, m3));
}

#define ZERO16 {0, 0, 0, 0, 0, 0, 0, 0, 0, 0, 0, 0, 0, 0, 0, 0}

// Compute one 32-doc-token tile against all 4 query blocks.
// Two acc chains live at a time (b pairs) -> 32 acc VGPRs.
#define TILE_COMPUTE(ABUF)                                                     \
  {                                                                            \
    floatx16 acc0 = ZERO16, acc1 = ZERO16;                                     \
    _Pragma("unroll") for (int k = 0; k < 8; ++k) {                            \
      acc0 = __builtin_amdgcn_mfma_f32_32x32x16_bf16(ABUF[k], qf[0][k], acc0, 0, 0, 0); \
      acc1 = __builtin_amdgcn_mfma_f32_32x32x16_bf16(ABUF[k], qf[1][k], acc1, 0, 0, 0); \
    }                                                                          \
    vmax[0] = fmaxf(vmax[0], rmax16(acc0));                                    \
    vmax[1] = fmaxf(vmax[1], rmax16(acc1));                                    \
    floatx16 acc2 = ZERO16, acc3 = ZERO16;                                     \
    _Pragma("unroll") for (int k = 0; k < 8; ++k) {                            \
      acc2 = __builtin_amdgcn_mfma_f32_32x32x16_bf16(ABUF[k], qf[2][k], acc2, 0, 0, 0); \
      acc3 = __builtin_amdgcn_mfma_f32_32x32x16_bf16(ABUF[k], qf[3][k], acc3, 0, 0, 0); \
    }                                                                          \
    vmax[2] = fmaxf(vmax[2], rmax16(acc2));                                    \
    vmax[3] = fmaxf(vmax[3], rmax16(acc3));                                    \
  }

__global__ __launch_bounds__(256, 2) void maxsim_kernel(float* __restrict__ out) {
  const ushort* qsb = g_bf;
  const ushort* psb = g_bf + QS_N;

  const int lane = threadIdx.x & 63;
  const int wave = threadIdx.x >> 6;

  // XCD-aware swizzle: all 16 blocks of doc c land on one XCD -> P_c stays
  // L2-resident (R4: FETCH 66 -> 10 MB).
  const int xcd = blockIdx.x & 7;
  const int slot = blockIdx.x >> 3;
  const int c = xcd * 8 + (slot >> 4);
  const int bg = slot & 15;
  const int b0 = bg * 4;
  const int row = lane & 31;         // A: s-row in tile; B frag: query token n
  const int koff = (lane >> 5) * 8;  // K-half selector

  // Stage Q in MFMA B-fragment order: frag id = (b*8 + k)*64 + lane, 16 B each.
  __shared__ ushort lds_q[4 * 8 * 64 * 8];  // 32 KiB
  {
    uint4* dst = (uint4*)lds_q;
#pragma unroll
    for (int i = 0; i < 8; ++i) {
      const int id = threadIdx.x + i * 256;  // 0..2047
      const int l = id & 63;
      const int k = (id >> 6) & 7;
      const int b = id >> 9;
      const int goff = ((b0 + b) * 32 + (l & 31)) * 128 + k * 16 + (l >> 5) * 8;
      dst[id] = *(const uint4*)(qsb + goff);  // consecutive 16 B: conflict-free
    }
  }
  __syncthreads();

  // Pull ALL Q fragments into registers ONCE (32 x ds_read_b128).
  // B-operand layout: B[n = lane&31][k = (lane>>5)*8 + j].
  const ushort* lq = lds_q + lane * 8;
  bf16x8 qf[4][8];
#pragma unroll
  for (int b = 0; b < 4; ++b)
#pragma unroll
    for (int k = 0; k < 8; ++k)
      qf[b][k] = *(const bf16x8*)(lq + (b * 8 + k) * 512);

  // Wave covers s in [wave*256, wave*256+256): 8 tiles of 32 doc tokens.
  const int pbase = (c * 1024 + wave * 256 + row) * 128 + koff;

  // Tile-0 A prefetch.
  bf16x8 a0[8], a1[8];
#pragma unroll
  for (int k = 0; k < 8; ++k) a0[k] = load_frag_bf16(psb + pbase + k * 16);

  float vmax[4];
#pragma unroll
  for (int b = 0; b < 4; ++b) vmax[b] = -3.4e38f;

#pragma unroll 1
  for (int t = 0; t < 8; t += 2) {
    // Prefetch tile t+1 into a1; compute tile t from a0.
#pragma unroll
    for (int k = 0; k < 8; ++k)
      a1[k] = load_frag_bf16(psb + pbase + (t + 1) * 4096 + k * 16);
    TILE_COMPUTE(a0)
    // Prefetch tile t+2 into a0 (wrap on last iter; harmless re-read).
    int t2 = t + 2;
    if (t2 > 7) t2 = 0;
#pragma unroll
    for (int k = 0; k < 8; ++k)
      a0[k] = load_frag_bf16(psb + pbase + t2 * 4096 + k * 16);
    // Compute tile t+1 from a1.
    TILE_COMPUTE(a1)
  }

  // Lanes l and l^32 hold complementary row-halves of the same query-token col.
#pragma unroll
  for (int b = 0; b < 4; ++b) vmax[b] = fmaxf(vmax[b], __shfl_xor(vmax[b], 32, 64));

  // Cross-wave max, then sum over the 32 query tokens.
  __shared__ float red[4][4][32];  // [wave][b][n]
  if (lane < 32) {
#pragma unroll
    for (int b = 0; b < 4; ++b) red[wave][b][lane] = vmax[b];
  }
  __syncthreads();
  if (threadIdx.x < 128) {
    const int b = threadIdx.x >> 5;
    const int n = threadIdx.x & 31;
    float m = fmaxf(fmaxf(red[0][b][n], red[1][b][n]), fmaxf(red[2][b][n], red[3][b][n]));
#pragma unroll
    for (int o = 16; o > 0; o >>= 1) m += __shfl_xor(m, o, 32);
    if (n == 0) out[(b0 + b) * 64 + c] = m;
  }
}

extern "C" void kernel_launch(void* const* d_in, const int* in_sizes, int n_in,
                              void* d_out, int out_size, void* d_ws, size_t ws_size,
                              hipStream_t stream) {
  const float* qs = (const float*)d_in[0];
  const float* ps = (const float*)d_in[1];
  float* out = (float*)d_out;
  (void)d_ws; (void)ws_size;  // deliberately unused: d_ws use triggers a 256 MiB poison fill

  const int n4 = (int)((QS_N + PS_N) / 4);
  cvt_kernel<<<(n4 + 255) / 256, 256, 0, stream>>>(qs, ps);
  maxsim_kernel<<<dim3(64 * 16), dim3(256), 0, stream>>>(out);
}

// Round 5
// 111.513 us; speedup vs baseline: 1.3395x; 1.0469x over previous
//
#include <hip/hip_runtime.h>
#include <stdint.h>

// ColBERT MaxSim on MI355X (gfx950), round 11.
// scores[b,c] = sum_n max_s dot(qs[b,n,:], ps[c,s,:])
// qs: (64, 32, 128) f32, ps: (64, 1024, 128) f32, out: (64, 64) f32.
//
// R10 post-mortem: poison gone, maxsim clean at 43.3 us / MfmaUtil 29% /
// Occ 16% / VGPR 120. Compute wall = 1.05M MFMA x 8cyc / 256 CU = 13.7 us.
// Cause of the 3x gap: allocator refuses qf[4][8] (4 rounds running), so
// every MFMA re-reads its 1 KB B-frag from LDS dependently (port ~8-12 cyc
// vs MFMA 8 cyc) with ~5 waves/CU of latency hiding.
//
// R11: restructure to fit the allocator's own 128-reg target instead of
// fighting it:
//   - wave owns 2 queries: qf[2][8] = 64 VGPRs, register-resident for free
//   - block = 4 waves = 8 queries x ALL 1024 doc tokens; grid = 64c x 8 = 512
//   - P tiles (32 tok x 128 dim bf16 = 8 KB) staged via global_load_lds
//     (zero VGPR), double-buffered, stored in MFMA-A-frag order
//     (chunk k*1024B + lane*16B): linear LDS dest (gload_lds requirement),
//     per-lane global src, contiguous conflict-free ds_read_b128
//   - 1 ds_read feeds 2 MFMAs -> LDS port 4+2 cyc/MFMA < 8 cyc MFMA wall
//   - epilogue: wave owns its queries over all s -> pure shuffle reduce
// Live set ~116 <= 128. Predict VGPR 110-128, no scratch, MfmaUtil 55-75%,
// maxsim 17-25 us. Failure signal: VGPR<100 => qf sunk again.

typedef __bf16 bf16x8 __attribute__((ext_vector_type(8)));
typedef float floatx16 __attribute__((ext_vector_type(16)));

#define QS_N (64u * 32u * 128u)    // 262144
#define PS_N (64u * 1024u * 128u)  // 8388608

// Static bf16 staging buffer: qs in [0, QS_N), ps in [QS_N, QS_N+PS_N).
// (d_ws deliberately unused: touching it triggers a 256 MiB poison fill.)
__device__ ushort g_bf[QS_N + PS_N];

__global__ __launch_bounds__(256) void cvt_kernel(const float* __restrict__ qs,
                                                  const float* __restrict__ ps) {
  const int nq4 = QS_N / 4;
  const int n4 = (QS_N + PS_N) / 4;
  int i = blockIdx.x * 256 + threadIdx.x;
  if (i >= n4) return;
  float4 f = (i < nq4) ? ((const float4*)qs)[i] : ((const float4*)ps)[i - nq4];
  union { ushort4 s; struct { __bf16 a, b, c, d; } h; } o;
  o.h.a = (__bf16)f.x; o.h.b = (__bf16)f.y; o.h.c = (__bf16)f.z; o.h.d = (__bf16)f.w;
  ((ushort4*)g_bf)[i] = o.s;
}

__device__ inline float rmax16(const floatx16& a) {
  // Nested fmaxf triples fuse to v_max3_f32.
  float m0 = fmaxf(fmaxf(a[0], a[1]), fmaxf(a[2], a[3]));
  float m1 = fmaxf(fmaxf(a[4], a[5]), fmaxf(a[6], a[7]));
  float m2 = fmaxf(fmaxf(a[8], a[9]), fmaxf(a[10], a[11]));
  float m3 = fmaxf(fmaxf(a[12], a[13]), fmaxf(a[14], a[15]));
  return fmaxf(fmaxf(m0, m1), fmaxf(m2, m3));
}

// global_load_lds: builtin takes AS1/AS3 pointers; C-style casts addrspacecast.
typedef __attribute__((address_space(1))) const void gas_t;
typedef __attribute__((address_space(3))) void las_t;
__device__ inline void gload_lds16(const ushort* g, ushort* l) {
  __builtin_amdgcn_global_load_lds((gas_t*)g, (las_t*)l, 16, 0, 0);
}

#define ZERO16 {0, 0, 0, 0, 0, 0, 0, 0, 0, 0, 0, 0, 0, 0, 0, 0}

__global__ __launch_bounds__(256) void maxsim_kernel(float* __restrict__ out) {
  const ushort* qsb = g_bf;
  const ushort* psb = g_bf + QS_N;

  const int lane = threadIdx.x & 63;
  const int wave = threadIdx.x >> 6;

  // XCD swizzle: the 8 blocks of doc c all land on XCD c>>3 -> P_c (256 KB
  // bf16) L2-resident after the first reader.
  const int xcd = blockIdx.x & 7;
  const int slot = blockIdx.x >> 3;   // 0..63
  const int c = xcd * 8 + (slot >> 3);
  const int bg = slot & 7;
  const int qb0 = bg * 8 + wave * 2;  // this wave's first query (of 2)

  const int row = lane & 31;          // A-frag: s-row; B-frag: query token n
  const int hi8 = (lane >> 5) * 8;    // K-half selector (elements)

  // Q B-frags straight global->reg (L2/L3-hot, 16 x dwordx4), resident all
  // kernel: qf[bb][k] holds Q[qb0+bb][n=row][k*16 + hi8 + 0..7].
  bf16x8 qf[2][8];
#pragma unroll
  for (int bb = 0; bb < 2; ++bb) {
    const ushort* q = qsb + ((qb0 + bb) * 32 + row) * 128 + hi8;
#pragma unroll
    for (int k = 0; k < 8; ++k)
      qf[bb][k] = *(const bf16x8*)(q + k * 16);
  }

  // P tile double-buffer, A-frag order: chunk j (=k) at j*1024B, lane at *16B.
  // Content: lds[j*512 + t*8 .. +8] = P[c][s0 + (t&31)][j*16 + (t>>5)*8 ..].
  __shared__ __align__(16) ushort lds_p[2][4096];  // 2 x 8 KiB

  // Per-lane global element offset (add s0*128 + j*16 per chunk).
  const int pg_lane = (c * 1024 + row) * 128 + hi8;

  // Prologue: stage tile 0 (wave w issues chunks 2w, 2w+1).
#pragma unroll
  for (int jj = 0; jj < 2; ++jj) {
    const int j = wave * 2 + jj;
    gload_lds16(psb + pg_lane + j * 16, &lds_p[0][j * 512]);
  }
  __syncthreads();

  float vmax0 = -3.4e38f, vmax1 = -3.4e38f;
  int cb = 0;

#pragma unroll 1
  for (int t = 0; t < 32; ++t) {
    // Stage tile t+1 into the other buffer (issued before compute so the
    // ~200-500 cyc L2 latency hides under this tile's 16 MFMAs).
    if (t < 31) {
      const int soff = (t + 1) * 32 * 128;
#pragma unroll
      for (int jj = 0; jj < 2; ++jj) {
        const int j = wave * 2 + jj;
        gload_lds16(psb + pg_lane + soff + j * 16, &lds_p[cb ^ 1][j * 512]);
      }
    }
    // Compute tile t: one contiguous ds_read_b128 feeds both queries' MFMAs.
    const ushort* lp = &lds_p[cb][0] + lane * 8;
    floatx16 acc0 = ZERO16, acc1 = ZERO16;
#pragma unroll
    for (int k = 0; k < 8; ++k) {
      bf16x8 af = *(const bf16x8*)(lp + k * 512);
      acc0 = __builtin_amdgcn_mfma_f32_32x32x16_bf16(af, qf[0][k], acc0, 0, 0, 0);
      acc1 = __builtin_amdgcn_mfma_f32_32x32x16_bf16(af, qf[1][k], acc1, 0, 0, 0);
    }
    vmax0 = fmaxf(vmax0, rmax16(acc0));
    vmax1 = fmaxf(vmax1, rmax16(acc1));
    // Barrier: staging of t+1 landed (implicit vmcnt drain) AND everyone is
    // done reading buffer cb before t+1 overwrites it.
    __syncthreads();
    cb ^= 1;
  }

  // acc D-layout: col = lane&31 = token n; lanes l, l^32 hold complementary
  // row-halves -> max-merge, then butterfly-sum the 32 tokens.
  vmax0 = fmaxf(vmax0, __shfl_xor(vmax0, 32, 64));
  vmax1 = fmaxf(vmax1, __shfl_xor(vmax1, 32, 64));
#pragma unroll
  for (int o = 16; o > 0; o >>= 1) {
    vmax0 += __shfl_xor(vmax0, o, 64);
    vmax1 += __shfl_xor(vmax1, o, 64);
  }
  if (lane == 0) {
    out[(qb0 + 0) * 64 + c] = vmax0;
    out[(qb0 + 1) * 64 + c] = vmax1;
  }
}

extern "C" void kernel_launch(void* const* d_in, const int* in_sizes, int n_in,
                              void* d_out, int out_size, void* d_ws, size_t ws_size,
                              hipStream_t stream) {
  const float* qs = (const float*)d_in[0];
  const float* ps = (const float*)d_in[1];
  float* out = (float*)d_out;
  (void)d_ws; (void)ws_size;  // d_ws use triggers a 256 MiB poison fill

  const int n4 = (int)((QS_N + PS_N) / 4);
  cvt_kernel<<<(n4 + 255) / 256, 256, 0, stream>>>(qs, ps);
  maxsim_kernel<<<dim3(512), dim3(256), 0, stream>>>(out);
}